// Round 1
// baseline (163.257 us; speedup 1.0000x reference)
//
#include <hip/hip_runtime.h>

// Problem constants (fixed by setup_inputs / reference)
#define BN  4       // batch
#define NPT 16384   // points per batch
#define NCC 1024    // FPS centroids (cap on unique orbit length)
#define KNN 32      // neighbors

// KNN select parameters
#define HBINS    2048   // 11-bit level-1 histogram
#define CCH      2      // centroids per chunk-block (keys fit in regs)
#define CAND_CAP 768    // boundary-bin candidate cap (overflow -> exact drill)

// Workspace layout (bytes). Total ~310 KB.
#define OFF_CCOUNT 0                          // BN ints
#define OFF_SCOUNT 64                         // BN ints
#define OFF_SBITS  128                        // BN*(NPT/32) u32 = 8 KB
#define OFF_POOL   (128 + BN*(NPT/32)*4)      // BN*NCC floats = 16 KB
#define OFF_CLIST  (OFF_POOL + BN*NCC*4)      // BN*NCC ints = 16 KB
#define OFF_H1     (OFF_CLIST + BN*NCC*4)     // BN*512 floats = 8 KB
#define OFF_H2     (OFF_H1 + BN*512*4)        // BN*256 floats = 4 KB
#define OFF_SLIST  (OFF_H2 + BN*256*4)        // BN*NPT ints = 256 KB

typedef short bf16x8 __attribute__((ext_vector_type(8)));
typedef float f32x4  __attribute__((ext_vector_type(4)));
typedef float f32x2  __attribute__((ext_vector_type(2)));

__device__ __forceinline__ short f2bf(float f) {   // RNE fp32 -> bf16
    unsigned u = __float_as_uint(f);
    return (short)((u + 0x7fffu + ((u >> 16) & 1u)) >> 16);
}
__device__ __forceinline__ bf16x8 cvt8(const float* __restrict__ p) {
    bf16x8 v;
#pragma unroll
    for (int j = 0; j < 8; ++j) v[j] = f2bf(p[j]);
    return v;
}

// ---------------------------------------------------------------------------
// FPS v7: max-then-locate argmax.
//  - distance phase carries only a packed running max (1 v_pk_max per 2 pts)
//    instead of cmp+2xcndmask per point (saves ~50 VALU instrs/thread/iter)
//  - value-only wave butterfly; per-wave LDS atomicMax on float bits
//    (distances >= +0 so uint order == float order)
//  - winning wave(s) locate the index by BIT-equality rescan of the stored
//    s-values + atomicMin => exactly the reference's first-index-attaining-max
//    (bit-equal nonneg floats <=> equal values; min index == strict-> winner)
//  - winner coords forwarded through LDS cand slots (ds_write_b128), removing
//    the serial ~250cy global centroid fetch from the critical path; count-
//    guarded so bit-equal ties fall back to the deterministic global load
//  - parity-rotated slots, 2 barriers/iter. Values bit-identical to v6.
// ---------------------------------------------------------------------------
__global__ __launch_bounds__(1024) void fps_kernel(const float* __restrict__ x,
    const int* __restrict__ far_init, int* __restrict__ clist, int* __restrict__ ccount,
    int* __restrict__ scount, unsigned* __restrict__ sbits, float* __restrict__ pool)
{
#pragma clang fp contract(off)
    const int b = blockIdx.x, t = threadIdx.x;
    __shared__ __align__(16) unsigned char seen[NPT];
    __shared__ unsigned vslot[2];
    __shared__ int      islot[2];
    __shared__ int      nmatch[2];
    __shared__ __align__(16) int4 cslot[2][4];

    // ---- workspace zeroing for this batch ----
    if (t < 512) sbits[b*(NPT/32) + t] = 0u;      // 512 u32
    pool[b*NCC + t] = 0.0f;                       // 1024 floats
    if (t == 0) { ccount[b] = 0; scount[b] = 0; }

    const float* xb = x + (size_t)b * NPT * 3;
    f32x2 px[8], py[8], pz[8];
#pragma unroll
    for (int r = 0; r < 8; ++r) {
        int ia = t + ((2*r) << 10), ib = ia + 1024;
        px[r] = f32x2{xb[ia*3+0], xb[ib*3+0]};
        py[r] = f32x2{xb[ia*3+1], xb[ib*3+1]};
        pz[r] = f32x2{xb[ia*3+2], xb[ib*3+2]};
    }
    ((uint4*)seen)[t] = make_uint4(0,0,0,0);      // 1024 * 16B = 16 KB
    if (t == 0) {
        vslot[0] = 0u;         vslot[1] = 0u;
        islot[0] = 0x7fffffff; islot[1] = 0x7fffffff;
        nmatch[0] = 0;         nmatch[1] = 0;
    }
    int prev_bx = far_init[b];                    // uniform (same global read)
    __syncthreads();
    int pbs = __builtin_amdgcn_readfirstlane(prev_bx);
    float cx = xb[pbs*3], cy = xb[pbs*3+1], cz = xb[pbs*3+2];

    int done = 0;
    for (int it = 0; it < NCC-1; ++it) {
        const int p = it & 1;
        const f32x2 cX = {cx, cx}, cY = {cy, cy}, cZ = {cz, cz};
        f32x2 sv[8];
        f32x2 rm = {0.0f, 0.0f};                  // distances >= 0, safe seed
#pragma unroll
        for (int r = 0; r < 8; ++r) {
            f32x2 dx = px[r] - cX;
            f32x2 dy = py[r] - cY;
            f32x2 dz = pz[r] - cZ;
            f32x2 m1 = dx * dx;
            f32x2 m2 = dy * dy;
            f32x2 m3 = dz * dz;
            f32x2 s  = (m1 + m2) + m3;            // exact grouping of reference
            sv[r] = s;
            rm.x = fmaxf(rm.x, s.x);
            rm.y = fmaxf(rm.y, s.y);
        }
        float tm = fmaxf(rm.x, rm.y);
#pragma unroll
        for (int m = 1; m < 64; m <<= 1)
            tm = fmaxf(tm, __shfl_xor(tm, m, 64)); // all lanes end wave-uniform
        if ((t & 63) == 0) atomicMax(&vslot[p], __float_as_uint(tm));
        if (t == 0) seen[prev_bx] = 1;            // pre-barrier write, no readers now
        __syncthreads();                          // B1: block max final
        const unsigned bmax = vslot[p];
        if (t == 0) {                             // prep other parity for next iter
            vslot[p^1] = 0u; islot[p^1] = 0x7fffffff; nmatch[p^1] = 0;
        }
        if (__float_as_uint(tm) == bmax) {        // wave-uniform: ~1 of 16 waves
            int   myidx = 0x7fffffff;
            float mx = 0.f, my = 0.f, mz = 0.f;
#pragma unroll
            for (int r = 0; r < 8; ++r) {
                int ia = t + ((2*r) << 10);
                if (__float_as_uint(sv[r].x) == bmax && ia < myidx)
                    { myidx = ia;        mx = px[r].x; my = py[r].x; mz = pz[r].x; }
                if (__float_as_uint(sv[r].y) == bmax && ia + 1024 < myidx)
                    { myidx = ia + 1024; mx = px[r].y; my = py[r].y; mz = pz[r].y; }
            }
            if (myidx != 0x7fffffff) {
                atomicMin(&islot[p], myidx);      // first-index tie-break
                int cs = atomicAdd(&nmatch[p], 1);
                if (cs < 4)
                    cslot[p][cs] = make_int4(myidx, __float_as_int(mx),
                                             __float_as_int(my), __float_as_int(mz));
            }
        }
        __syncthreads();                          // B2: winner index + coords final
        const int bx = islot[p];
        if (seen[bx]) { done = 1; break; }        // uniform (stable post-barrier)
        prev_bx = bx;
        const int nm = nmatch[p] < 4 ? nmatch[p] : 4;
        bool got = false;
        float nx = 0.f, ny = 0.f, nz = 0.f;
#pragma unroll
        for (int csi = 0; csi < 4; ++csi) {       // LDS broadcast, typ. 1 slot
            if (csi < nm) {
                int4 v = cslot[p][csi];
                if (v.x == bx) {
                    nx = __int_as_float(v.y); ny = __int_as_float(v.z);
                    nz = __int_as_float(v.w); got = true;
                }
            }
        }
        if (got) { cx = nx; cy = ny; cz = nz; }   // fast path: no L2 round-trip
        else {                                    // tie/overflow fallback (rare)
            int bxs = __builtin_amdgcn_readfirstlane(bx);
            cx = xb[bxs*3]; cy = xb[bxs*3+1]; cz = xb[bxs*3+2];
        }
    }
    if (!done && t == 0) seen[prev_bx] = 1;       // full-length orbit: mark last
    __syncthreads();
#pragma unroll
    for (int j = 0; j < 16; ++j) {
        int idx = t + (j << 10);
        if (seen[idx]) {
            int pos = atomicAdd(&ccount[b], 1);
            clist[b * NCC + pos] = idx;
        }
    }
}

// ---------------------------------------------------------------------------
// KNN v5 (proven R8): chunk-parallel, register-cached keys (compute once,
// reuse in sweeps 2/3). Exact tau; drill-down recomputes. Tail-clamp dup.
// ---------------------------------------------------------------------------
__device__ __forceinline__ unsigned key_of(float px, float py, float pz, float xn,
                                           float cx, float cy, float cz, float cn)
{
    float dot = __fadd_rn(__fadd_rn(__fmul_rn(cx,px), __fmul_rn(cy,py)), __fmul_rn(cz,pz));
    float d2  = __fsub_rn(__fadd_rn(cn, xn), __fmul_rn(2.0f, dot));
    unsigned u = __float_as_uint(d2);
    return u ^ ((u >> 31) ? 0xFFFFFFFFu : 0x80000000u);
}

__device__ __forceinline__ void wave_scan_bins(const unsigned* __restrict__ H,
    int nbins, int rem, int lane, int* __restrict__ out_bin, int* __restrict__ out_below)
{
    int per = nbins >> 6;
    int base = lane * per;
    unsigned part = 0;
    for (int q = 0; q < per; ++q) part += H[base + q];
    unsigned inc = part;
#pragma unroll
    for (int m = 1; m < 64; m <<= 1) {
        unsigned u = __shfl_up(inc, m, 64);
        if (lane >= m) inc += u;
    }
    unsigned exc = inc - part;
    unsigned long long mk = __ballot(exc < (unsigned)rem && inc >= (unsigned)rem);
    int src = __ffsll((long long)mk) - 1;
    if (lane == src) {
        unsigned run = exc; int bb = base;
        for (int q = 0; q < per; ++q) {
            unsigned h = H[base + q];
            if (run + h >= (unsigned)rem) { bb = base + q; break; }
            run += h;
        }
        *out_bin = bb; *out_below = (int)run;
    }
}

__global__ __launch_bounds__(1024) void knn_kernel(const float* __restrict__ x,
    const int* __restrict__ clist, const int* __restrict__ ccount,
    unsigned* __restrict__ sbits, int* __restrict__ slist, int* __restrict__ scount)
{
    const int b = blockIdx.y, t = threadIdx.x;
    const int lane = t & 63, w = t >> 6;
    const int cnt = ccount[b];
    const int cbase = blockIdx.x * CCH;
    if (cbase >= cnt) return;                  // uniform exit, before any barrier
    const float* xb = x + (size_t)b * NPT * 3;

    __shared__ unsigned hist[CCH * HBINS];     // 16 KB
    __shared__ unsigned cand[CCH * CAND_CAP];  // 6 KB
    __shared__ float cpx[CCH], cpy[CCH], cpz[CCH], cpn[CCH];
    __shared__ unsigned candCnt[CCH];
    __shared__ int s_bb[CCH], s_below[CCH], s_rrem[CCH], s_need[CCH], s_pref[CCH];
    __shared__ unsigned s_tau[CCH];
    __shared__ int s_tbin, s_tbelow;

    if (t < CCH) {
        int ci = clist[b * NCC + min(cbase + t, cnt - 1)];   // tail-clamp dup
        float cx = xb[ci*3], cy = xb[ci*3+1], cz = xb[ci*3+2];
        cpx[t] = cx; cpy[t] = cy; cpz[t] = cz;
        cpn[t] = __fadd_rn(__fadd_rn(__fmul_rn(cx,cx), __fmul_rn(cy,cy)), __fmul_rn(cz,cz));
        candCnt[t] = 0;
    }
    for (int i = t; i < CCH * HBINS; i += 1024) hist[i] = 0;
    __syncthreads();

    // Sweep 1: compute keys ONCE into registers + build histograms.
    unsigned keys[NPT/1024][CCH];              // 16 x 2 u32 = 32 VGPRs
#pragma unroll
    for (int j = 0; j < NPT/1024; ++j) {
        int i = t + (j << 10);
        float px = xb[i*3], py = xb[i*3+1], pz = xb[i*3+2];
        float xn = __fadd_rn(__fadd_rn(__fmul_rn(px,px), __fmul_rn(py,py)), __fmul_rn(pz,pz));
#pragma unroll
        for (int c = 0; c < CCH; ++c) {
            unsigned key = key_of(px,py,pz,xn, cpx[c],cpy[c],cpz[c],cpn[c]);
            keys[j][c] = key;
            atomicAdd(&hist[c*HBINS + (key >> 21)], 1u);
        }
    }
    __syncthreads();

    if (w < CCH)
        wave_scan_bins(&hist[w*HBINS], HBINS, KNN, lane, &s_bb[w], &s_below[w]);
    __syncthreads();
    if (t < CCH) s_rrem[t] = KNN - s_below[t];
    __syncthreads();

    // Sweep 2 (registers only): collect candidate keys in boundary bins.
#pragma unroll
    for (int j = 0; j < NPT/1024; ++j) {
#pragma unroll
        for (int c = 0; c < CCH; ++c) {
            unsigned key = keys[j][c];
            if ((int)(key >> 21) == s_bb[c]) {
                unsigned pos = atomicAdd(&candCnt[c], 1u);
                if (pos < CAND_CAP) cand[c*CAND_CAP + pos] = key;
            }
        }
    }
    __syncthreads();

    // Exact tau: rank-select (rrem-th smallest with multiplicity) per wave.
    if (w < CCH) {
        unsigned cc = candCnt[w];
        if (cc <= CAND_CAP) {
            int r = s_rrem[w] - 1;
            const unsigned* C = &cand[w*CAND_CAP];
            for (int idx = lane; idx < (int)cc; idx += 64) {
                unsigned k = C[idx]; int rank = 0;
                for (int q = 0; q < (int)cc; ++q) {
                    unsigned kq = C[q];
                    rank += (kq < k || (kq == k && q < idx)) ? 1 : 0;
                }
                if (rank == r) s_tau[w] = k;
            }
            if (lane == 0) s_need[w] = 0;
        } else if (lane == 0) s_need[w] = 1;
    }
    __syncthreads();

    // Rare exact drill-down for overflowed boundary bins (guaranteed exact).
    for (int c = 0; c < CCH; ++c) {
        if (s_need[c]) {
            const float cx = cpx[c], cy = cpy[c], cz = cpz[c], cn = cpn[c];
            for (int i = t; i < HBINS; i += 1024) hist[i] = 0;
            __syncthreads();
            for (int j = 0; j < NPT/1024; ++j) {
                int i = t + (j << 10);
                float px = xb[i*3], py = xb[i*3+1], pz = xb[i*3+2];
                float xn = __fadd_rn(__fadd_rn(__fmul_rn(px,px), __fmul_rn(py,py)), __fmul_rn(pz,pz));
                unsigned key = key_of(px,py,pz,xn, cx,cy,cz,cn);
                if ((int)(key >> 21) == s_bb[c]) atomicAdd(&hist[(key >> 10) & 2047u], 1u);
            }
            __syncthreads();
            if (w == 0) wave_scan_bins(hist, HBINS, s_rrem[c], lane, &s_tbin, &s_tbelow);
            __syncthreads();
            if (t == 0) { s_pref[c] = (s_bb[c] << 11) | s_tbin; s_rrem[c] -= s_tbelow; }
            __syncthreads();
            for (int i = t; i < 1024; i += 1024) hist[i] = 0;
            __syncthreads();
            for (int j = 0; j < NPT/1024; ++j) {
                int i = t + (j << 10);
                float px = xb[i*3], py = xb[i*3+1], pz = xb[i*3+2];
                float xn = __fadd_rn(__fadd_rn(__fmul_rn(px,px), __fmul_rn(py,py)), __fmul_rn(pz,pz));
                unsigned key = key_of(px,py,pz,xn, cx,cy,cz,cn);
                if ((int)(key >> 10) == s_pref[c]) atomicAdd(&hist[key & 1023u], 1u);
            }
            __syncthreads();
            if (w == 0) wave_scan_bins(hist, 1024, s_rrem[c], lane, &s_tbin, &s_tbelow);
            __syncthreads();
            if (t == 0) s_tau[c] = (((unsigned)s_pref[c]) << 10) | (unsigned)s_tbin;
            __syncthreads();
        }
    }
    __syncthreads();

    // Sweep 3 (registers only): union-mark + build compacted list (deduped).
#pragma unroll
    for (int j = 0; j < NPT/1024; ++j) {
        int i = t + (j << 10);
        bool sel = false;
#pragma unroll
        for (int c = 0; c < CCH; ++c) sel |= (keys[j][c] <= s_tau[c]);
        if (sel) {
            unsigned bit = 1u << (i & 31);
            unsigned old = atomicOr(&sbits[b*(NPT/32) + (i >> 5)], bit);
            if (!(old & bit)) {
                int pos = atomicAdd(&scount[b], 1);
                slist[b * NPT + pos] = i;
            }
        }
    }
}

// ---------------------------------------------------------------------------
// MLP v4 (proven R6): MFMA 16x16x32 bf16, weights persistent in VGPR B-frags.
// ---------------------------------------------------------------------------
#define MFMA16(a, bfr, c) __builtin_amdgcn_mfma_f32_16x16x32_bf16(a, bfr, c, 0, 0, 0)

__global__ __launch_bounds__(1024) void mlp_kernel(const float* __restrict__ x,
    const int* __restrict__ sel_list, const int* __restrict__ sel_count,
    const float* __restrict__ w1, const float* __restrict__ b1,
    const float* __restrict__ w2, const float* __restrict__ b2,
    const float* __restrict__ w3, const float* __restrict__ b3,
    const float* __restrict__ w4, const float* __restrict__ b4,
    const float* __restrict__ w5, const float* __restrict__ b5,
    float* __restrict__ pool)
{
    const int b = blockIdx.y, z = blockIdx.z, t = threadIdx.x;
    const int cnt = sel_count[b];
    if ((blockIdx.x << 6) >= cnt) return;      // uniform, before any barrier
    const int lane = t & 63;
    const int w    = __builtin_amdgcn_readfirstlane(t >> 6);  // 0..15
    const int m    = lane & 15, quad = lane >> 4;

    __shared__ __align__(16) short A1[64 * 72];    // 9 KB
    __shared__ __align__(16) short A2[64 * 72];    // 9 KB
    __shared__ __align__(16) short A3[64 * 136];   // 17 KB
    __shared__ float sx[3 * 64];

    const int ocA = (w >> 2) * 16 + m;             // L2/L3 oc (wave>>2 = oc_tile)
    bf16x8 bw2[2], bw3[2], bw4[2][2], bw5[4];
#pragma unroll
    for (int ks = 0; ks < 2; ++ks) {
        bw2[ks] = cvt8(w2 + ocA*64 + ks*32 + quad*8);
        bw3[ks] = cvt8(w3 + ocA*64 + ks*32 + quad*8);
    }
    int oc4i[2];
#pragma unroll
    for (int r2 = 0; r2 < 2; ++r2) {
        oc4i[r2] = ((w >> 2) + 4*r2) * 16 + m;
#pragma unroll
        for (int ks = 0; ks < 2; ++ks)
            bw4[r2][ks] = cvt8(w4 + oc4i[r2]*64 + ks*32 + quad*8);
    }
    const int oc5 = z*256 + w*16 + m;
#pragma unroll
    for (int ks = 0; ks < 4; ++ks)
        bw5[ks] = cvt8(w5 + oc5*128 + ks*32 + quad*8);
    const float bias2 = b2[ocA], bias3 = b3[ocA];
    const float bias4_0 = b4[oc4i[0]], bias4_1 = b4[oc4i[1]];
    const float bias5 = b5[oc5];
    float w1v[4][3], b1v[4];
#pragma unroll
    for (int i = 0; i < 4; ++i) {
        int oc = w*4 + i;
        w1v[i][0] = w1[oc*3+0]; w1v[i][1] = w1[oc*3+1]; w1v[i][2] = w1[oc*3+2];
        b1v[i] = b1[oc];
    }
    const int pt0 = (w & 3) * 16;                  // pt tile for L2/L3/L4

    for (int base = blockIdx.x << 6; base < cnt; base += (32 << 6)) {
        const int npts = min(64, cnt - base);
        __syncthreads();                            // prev tile fully consumed
        if (t < 64) {
            int idx = sel_list[b * NPT + base + min(t, npts - 1)];  // pad = dup last
            const float* xp = x + ((size_t)b * NPT + idx) * 3;
            sx[t] = xp[0]; sx[64 + t] = xp[1]; sx[128 + t] = xp[2];
        }
        __syncthreads();
        {   // L1: 3->64, fp32 VALU, write bf16 [pt][72]
            float x0 = sx[lane], x1 = sx[64 + lane], x2 = sx[128 + lane];
#pragma unroll
            for (int i = 0; i < 4; ++i) {
                float acc = fmaf(x2, w1v[i][2], fmaf(x1, w1v[i][1],
                             fmaf(x0, w1v[i][0], b1v[i])));
                A1[lane*72 + w*4 + i] = f2bf(fmaxf(acc, 0.0f));
            }
        }
        __syncthreads();
        {   // L2: A1 -> A2 (64->64)
            bf16x8 a0 = *(const bf16x8*)&A1[(pt0 + m)*72 + quad*8];
            bf16x8 a1 = *(const bf16x8*)&A1[(pt0 + m)*72 + 32 + quad*8];
            f32x4 d = {0.f, 0.f, 0.f, 0.f};
            d = MFMA16(a0, bw2[0], d);
            d = MFMA16(a1, bw2[1], d);
#pragma unroll
            for (int r = 0; r < 4; ++r)
                A2[(pt0 + quad*4 + r)*72 + ocA] = f2bf(fmaxf(d[r] + bias2, 0.0f));
        }
        __syncthreads();
        {   // L3: A2 -> A1 (64->64)
            bf16x8 a0 = *(const bf16x8*)&A2[(pt0 + m)*72 + quad*8];
            bf16x8 a1 = *(const bf16x8*)&A2[(pt0 + m)*72 + 32 + quad*8];
            f32x4 d = {0.f, 0.f, 0.f, 0.f};
            d = MFMA16(a0, bw3[0], d);
            d = MFMA16(a1, bw3[1], d);
#pragma unroll
            for (int r = 0; r < 4; ++r)
                A1[(pt0 + quad*4 + r)*72 + ocA] = f2bf(fmaxf(d[r] + bias3, 0.0f));
        }
        __syncthreads();
        {   // L4: A1 -> A3 (64->128), 2 oc-tiles per wave
            bf16x8 a0 = *(const bf16x8*)&A1[(pt0 + m)*72 + quad*8];
            bf16x8 a1 = *(const bf16x8*)&A1[(pt0 + m)*72 + 32 + quad*8];
#pragma unroll
            for (int r2 = 0; r2 < 2; ++r2) {
                f32x4 d = {0.f, 0.f, 0.f, 0.f};
                d = MFMA16(a0, bw4[r2][0], d);
                d = MFMA16(a1, bw4[r2][1], d);
                float bs = r2 ? bias4_1 : bias4_0;
#pragma unroll
                for (int r = 0; r < 4; ++r)
                    A3[(pt0 + quad*4 + r)*136 + oc4i[r2]] = f2bf(fmaxf(d[r] + bs, 0.0f));
            }
        }
        __syncthreads();
        {   // L5 (128 -> this block's 256-oc slice) + max-pool
            float vm = 0.0f;                        // relu outputs >= 0
#pragma unroll
            for (int pt4 = 0; pt4 < 4; ++pt4) {
                const int q0 = pt4 * 16;
                f32x4 d = {0.f, 0.f, 0.f, 0.f};
#pragma unroll
                for (int ks = 0; ks < 4; ++ks) {
                    bf16x8 a = *(const bf16x8*)&A3[(q0 + m)*136 + ks*32 + quad*8];
                    d = MFMA16(a, bw5[ks], d);
                }
#pragma unroll
                for (int r = 0; r < 4; ++r)
                    vm = fmaxf(vm, fmaxf(d[r] + bias5, 0.0f));
            }
            vm = fmaxf(vm, __shfl_xor(vm, 16, 64));
            vm = fmaxf(vm, __shfl_xor(vm, 32, 64));
            if (lane < 16)
                atomicMax((int*)&pool[b*NCC + z*256 + w*16 + lane], __float_as_int(vm));
        }
    }
}

// ---------------------------------------------------------------------------
// Head, split by OUTPUT ROWS so weight traffic scales with block count
// (R8 lesson: fused head = 4 CUs streaming 2.5 MB each = 47 us).
// head1: FC1 1024->512, grid (16,BN), 32 rows/block (2 rows/wave).
// ---------------------------------------------------------------------------
__global__ __launch_bounds__(1024) void head1_kernel(const float* __restrict__ pool,
    const float* __restrict__ fw1, const float* __restrict__ fb1,
    float* __restrict__ h1g)
{
    const int bo = blockIdx.x, b = blockIdx.y, t = threadIdx.x;
    const int lane = t & 63, w = t >> 6;
    __shared__ float g[1024];
    g[t] = pool[b*NCC + t];
    __syncthreads();
#pragma unroll
    for (int i = 0; i < 2; ++i) {
        int o = bo * 32 + w * 2 + i;
        float acc = 0.0f;
#pragma unroll
        for (int j = 0; j < 16; ++j) {
            int k = lane + (j << 6);
            acc += g[k] * fw1[o*1024 + k];
        }
#pragma unroll
        for (int m = 1; m < 64; m <<= 1) acc += __shfl_xor(acc, m, 64);
        if (lane == 0) h1g[b*512 + o] = fmaxf(acc + fb1[o], 0.0f);
    }
}

// head2: FC2 512->256, grid (8,BN), 32 rows/block (2 rows/wave).
__global__ __launch_bounds__(1024) void head2_kernel(const float* __restrict__ h1g,
    const float* __restrict__ fw2, const float* __restrict__ fb2,
    float* __restrict__ h2g)
{
    const int bo = blockIdx.x, b = blockIdx.y, t = threadIdx.x;
    const int lane = t & 63, w = t >> 6;
    __shared__ float h1[512];
    if (t < 512) h1[t] = h1g[b*512 + t];
    __syncthreads();
#pragma unroll
    for (int i = 0; i < 2; ++i) {
        int o = bo * 32 + w * 2 + i;
        float acc = 0.0f;
#pragma unroll
        for (int j = 0; j < 8; ++j) {
            int k = lane + (j << 6);
            acc += h1[k] * fw2[o*512 + k];
        }
#pragma unroll
        for (int m = 1; m < 64; m <<= 1) acc += __shfl_xor(acc, m, 64);
        if (lane == 0) h2g[b*256 + o] = fmaxf(acc + fb2[o], 0.0f);
    }
}

// head3: FC3 256->3. One block per batch (tiny).
__global__ __launch_bounds__(256) void head3_kernel(const float* __restrict__ h2g,
    const float* __restrict__ fw3, const float* __restrict__ fb3,
    float* __restrict__ out)
{
    const int b = blockIdx.x, t = threadIdx.x;
    const int lane = t & 63, w = t >> 6;
    __shared__ float h2[256];
    h2[t] = h2g[b*256 + t];
    __syncthreads();
    if (w < 3) {
        float acc = 0.0f;
#pragma unroll
        for (int j = 0; j < 4; ++j) {
            int k = lane + (j << 6);
            acc += h2[k] * fw3[w*256 + k];
        }
#pragma unroll
        for (int m = 1; m < 64; m <<= 1) acc += __shfl_xor(acc, m, 64);
        if (lane == 0) out[b*3 + w] = acc + fb3[w];
    }
}

extern "C" void kernel_launch(void* const* d_in, const int* in_sizes, int n_in,
                              void* d_out, int out_size, void* d_ws, size_t ws_size,
                              hipStream_t stream)
{
    const float* x    = (const float*)d_in[0];
    const int*   far0 = (const int*)  d_in[1];
    const float *w1 = (const float*)d_in[2],  *b1 = (const float*)d_in[3];
    const float *w2 = (const float*)d_in[4],  *b2 = (const float*)d_in[5];
    const float *w3 = (const float*)d_in[6],  *b3 = (const float*)d_in[7];
    const float *w4 = (const float*)d_in[8],  *b4 = (const float*)d_in[9];
    const float *w5 = (const float*)d_in[10], *b5 = (const float*)d_in[11];
    const float *fw1 = (const float*)d_in[12], *fb1 = (const float*)d_in[13];
    const float *fw2 = (const float*)d_in[14], *fb2 = (const float*)d_in[15];
    const float *fw3 = (const float*)d_in[16], *fb3 = (const float*)d_in[17];

    char* ws = (char*)d_ws;
    int*      ccount = (int*)     (ws + OFF_CCOUNT);
    int*      scount = (int*)     (ws + OFF_SCOUNT);
    unsigned* sbits  = (unsigned*)(ws + OFF_SBITS);
    float*    pool   = (float*)   (ws + OFF_POOL);
    int*      clist  = (int*)     (ws + OFF_CLIST);
    float*    h1g    = (float*)   (ws + OFF_H1);
    float*    h2g    = (float*)   (ws + OFF_H2);
    int*      slist  = (int*)     (ws + OFF_SLIST);

    // workspace zeroing is folded into fps_kernel
    fps_kernel<<<BN, 1024, 0, stream>>>(x, far0, clist, ccount, scount, sbits, pool);
    knn_kernel<<<dim3(NCC/CCH, BN), 1024, 0, stream>>>(x, clist, ccount, sbits, slist, scount);
    mlp_kernel<<<dim3(32, BN, 4), 1024, 0, stream>>>(x, slist, scount,
        w1,b1, w2,b2, w3,b3, w4,b4, w5,b5, pool);
    head1_kernel<<<dim3(16, BN), 1024, 0, stream>>>(pool, fw1, fb1, h1g);
    head2_kernel<<<dim3(8, BN), 1024, 0, stream>>>(h1g, fw2, fb2, h2g);
    head3_kernel<<<BN, 256, 0, stream>>>(h2g, fw3, fb3, (float*)d_out);
}